// Round 2
// baseline (693.997 us; speedup 1.0000x reference)
//
#include <hip/hip_runtime.h>
#include <hip/hip_bf16.h>
#include <math.h>

#define B_ 8
#define M_ 4096
#define D_ 1024
#define NP_ 128
#define TEMP_ 0.1f
#define EPS_ 1e-12f

typedef __attribute__((ext_vector_type(8))) short bf16x8;
typedef __attribute__((ext_vector_type(4))) float f32x4;

__device__ __forceinline__ unsigned short f2bf(float f) {
    union { float f; unsigned int u; } v; v.f = f;
    unsigned int u = v.u;
    u += 0x7fff + ((u >> 16) & 1);  // RNE
    return (unsigned short)(u >> 16);
}

// stage 128 rows x 64 bytes into LDS (8 KB), via global_load_lds width 16.
__device__ __forceinline__ void stage_tile(const char* gbase, size_t row_stride,
                                           char* lds, int tid) {
    const int lane = tid & 63, w = tid >> 6;
#pragma unroll
    for (int t = 0; t < 2; ++t) {
        const int row = w * 32 + t * 16 + (lane >> 2);
        const char* g = gbase + (size_t)row * row_stride + (lane & 3) * 16;
        char* l = lds + (w * 32 + t * 16) * 64 + lane * 16;
        __builtin_amdgcn_global_load_lds((const __attribute__((address_space(1))) unsigned int*)g,
                                         (__attribute__((address_space(3))) unsigned int*)l,
                                         16, 0, 0);
    }
}

// stage 64 rows x 64 bytes into LDS (4 KB)
__device__ __forceinline__ void stage_rows64(const char* gbase, size_t row_stride,
                                             char* lds, int tid) {
    const int lane = tid & 63, w = tid >> 6;
    const int row = w * 16 + (lane >> 2);
    const char* g = gbase + (size_t)row * row_stride + (lane & 3) * 16;
    char* l = lds + (w * 16) * 64 + lane * 16;
    __builtin_amdgcn_global_load_lds((const __attribute__((address_space(1))) unsigned int*)g,
                                     (__attribute__((address_space(3))) unsigned int*)l,
                                     16, 0, 0);
}

template <int NI, int NJ>
__device__ __forceinline__ void mfma_tile(const char* At, const char* Bt,
                                          f32x4 (&acc)[NI][NJ], int wm, int wn,
                                          int fr, int q) {
    bf16x8 a[NI], bb[NJ];
#pragma unroll
    for (int i = 0; i < NI; ++i)
        a[i] = *(const bf16x8*)(At + (wm + i * 16 + fr) * 64 + q * 16);
#pragma unroll
    for (int j = 0; j < NJ; ++j)
        bb[j] = *(const bf16x8*)(Bt + (wn + j * 16 + fr) * 64 + q * 16);
#pragma unroll
    for (int i = 0; i < NI; ++i)
#pragma unroll
        for (int j = 0; j < NJ; ++j)
            acc[i][j] = __builtin_amdgcn_mfma_f32_16x16x32_bf16(a[i], bb[j], acc[i][j], 0, 0, 0);
}

// ---------------- prep: rinv + bf16 cast (xbf[m][d]) + bf16 transpose (xbfT[d][m]) ----------------
__global__ __launch_bounds__(256) void k_prepT(const float* __restrict__ x,
                                               unsigned short* __restrict__ xbf,
                                               unsigned short* __restrict__ xbfT,
                                               float* __restrict__ rinv) {
    const int p = blockIdx.x;
    const int b = p >> 6, m0 = (p & 63) * 64;
    const int tid = threadIdx.x;
    const int mg = tid >> 4;   // 0..15
    const int d4 = tid & 15;   // 0..15
    __shared__ unsigned short lt[2][64][72];  // double-buffered: one barrier per chunk
    float ss[4] = {0.f, 0.f, 0.f, 0.f};
    for (int ch = 0; ch < 16; ++ch) {
        const int d0 = ch * 64;
        const int buf = ch & 1;
#pragma unroll
        for (int ii = 0; ii < 4; ++ii) {
            const int m = mg + ii * 16;
            float4 v = *(const float4*)(x + ((size_t)(b * M_ + m0 + m)) * D_ + d0 + d4 * 4);
            ss[ii] += v.x * v.x + v.y * v.y + v.z * v.z + v.w * v.w;
            ushort4 bv;
            bv.x = f2bf(v.x); bv.y = f2bf(v.y); bv.z = f2bf(v.z); bv.w = f2bf(v.w);
            *(ushort4*)(xbf + ((size_t)(b * M_ + m0 + m)) * D_ + d0 + d4 * 4) = bv;
            lt[buf][d4 * 4 + 0][m] = bv.x;
            lt[buf][d4 * 4 + 1][m] = bv.y;
            lt[buf][d4 * 4 + 2][m] = bv.z;
            lt[buf][d4 * 4 + 3][m] = bv.w;
        }
        __syncthreads();
        const int dl = tid >> 2, mq = (tid & 3) * 16;
        bf16x8 v0 = *(const bf16x8*)&lt[buf][dl][mq];
        bf16x8 v1 = *(const bf16x8*)&lt[buf][dl][mq + 8];
        unsigned short* to = xbfT + ((size_t)(b * D_ + d0 + dl)) * M_ + m0 + mq;
        *(bf16x8*)(to) = v0;
        *(bf16x8*)(to + 8) = v1;
        // no second barrier: next chunk writes the other buffer
    }
#pragma unroll
    for (int ii = 0; ii < 4; ++ii) {
        float s = ss[ii];
        s += __shfl_down(s, 8, 16);
        s += __shfl_down(s, 4, 16);
        s += __shfl_down(s, 2, 16);
        s += __shfl_down(s, 1, 16);
        if (d4 == 0)
            rinv[b * M_ + m0 + mg + ii * 16] = 1.0f / (fmaxf(sqrtf(s), EPS_) * TEMP_);
    }
}

// ---------------- phi normalize -> phinT[np][d] bf16 ----------------
__global__ void k_phin(const float* __restrict__ phi, const float* __restrict__ scale,
                       unsigned short* __restrict__ phinT) {
    const int np = blockIdx.x, tid = threadIdx.x;
    float ss = 0.f;
    for (int d = tid; d < D_; d += 256) {
        float v = phi[d * NP_ + np];
        ss += v * v;
    }
    __shared__ float red[256];
    red[tid] = ss;
    __syncthreads();
    for (int s = 128; s > 0; s >>= 1) {
        if (tid < s) red[tid] += red[tid + s];
        __syncthreads();
    }
    float inv = scale[0] / fmaxf(sqrtf(red[0]), EPS_);
    for (int d = tid; d < D_; d += 256) phinT[np * D_ + d] = f2bf(phi[d * NP_ + np] * inv);
}

// ---------------- GEMM1: logitsT[b][np][m] = (phinT . xbf) * rinv[m] ----------------
// operand-swapped: A = xbf (m rows), B = phinT (np rows) -> C[m][np], float4 stores along m.
// tile 64m x 64np, grid (64, 2, 8) = 1024 blocks (4 blocks/CU)
__global__ __launch_bounds__(256) void k_logits(const unsigned short* __restrict__ phinT,
                                                const unsigned short* __restrict__ xbf,
                                                const float* __restrict__ rinv,
                                                float* __restrict__ logitsT) {
    const int m0 = blockIdx.x * 64;
    const int np0 = blockIdx.y * 64;
    const int b = blockIdx.z;
    const int tid = threadIdx.x, lane = tid & 63, w = tid >> 6;
    __shared__ char At[2][4096], Bt[2][4096];
    f32x4 acc[2][2] = {};
    const char* abase = (const char*)(xbf + ((size_t)b * M_ + m0) * D_);   // 64 m rows, stride 2048
    const char* bbase = (const char*)(phinT + (size_t)np0 * D_);           // 64 np rows, stride 2048
    const int wmm = (w & 1) * 32, wnn = (w >> 1) * 32;
    const int fr = lane & 15, q = lane >> 4;
    stage_rows64(abase, 2048, At[0], tid);
    stage_rows64(bbase, 2048, Bt[0], tid);
    __syncthreads();
    int cur = 0;
    for (int k0 = 64; k0 < 2048; k0 += 64) {
        stage_rows64(abase + k0, 2048, At[cur ^ 1], tid);
        stage_rows64(bbase + k0, 2048, Bt[cur ^ 1], tid);
        mfma_tile<2, 2>(At[cur], Bt[cur], acc, wmm, wnn, fr, q);
        __syncthreads();
        cur ^= 1;
    }
    mfma_tile<2, 2>(At[cur], Bt[cur], acc, wmm, wnn, fr, q);
    // C[m][np]: m = wmm + i*16 + q*4 + reg, np = np0 + wnn + j*16 + fr
#pragma unroll
    for (int i = 0; i < 2; ++i) {
        const int mm = wmm + i * 16 + q * 4;
        const float4 rv = *(const float4*)(rinv + (size_t)b * M_ + m0 + mm);
#pragma unroll
        for (int j = 0; j < 2; ++j) {
            const int np = np0 + wnn + j * 16 + fr;
            float4 o;
            o.x = acc[i][j][0] * rv.x;
            o.y = acc[i][j][1] * rv.y;
            o.z = acc[i][j][2] * rv.z;
            o.w = acc[i][j][3] * rv.w;
            *(float4*)(logitsT + ((size_t)b * NP_ + np) * M_ + m0 + mm) = o;
        }
    }
}

// ---------------- dispatch softmax stats over m (rows of logitsT) ----------------
__global__ void k_colstats(const float* __restrict__ logitsT, float* __restrict__ cmax,
                           float* __restrict__ cinv) {
    const int row = blockIdx.x * 4 + (threadIdx.x >> 6);  // b*128+np
    const int lane = threadIdx.x & 63;
    const float4* base = (const float4*)(logitsT + (size_t)row * M_);
    float mx = -1e30f, sm = 0.f;
#pragma unroll 4
    for (int it = 0; it < 16; ++it) {
        float4 v = base[lane + 64 * it];
        float lm = fmaxf(fmaxf(v.x, v.y), fmaxf(v.z, v.w));
        float nm = fmaxf(mx, lm);
        sm = sm * __expf(mx - nm) + __expf(v.x - nm) + __expf(v.y - nm) + __expf(v.z - nm) +
             __expf(v.w - nm);
        mx = nm;
    }
    for (int off = 32; off > 0; off >>= 1) {
        float om = __shfl_down(mx, off), os = __shfl_down(sm, off);
        float nm = fmaxf(mx, om);
        sm = sm * __expf(mx - nm) + os * __expf(om - nm);
        mx = nm;
    }
    if (lane == 0) {
        cmax[row] = mx;
        cinv[row] = 1.0f / sm;
    }
}

// ---------------- weights: dvalT[np][m] bf16 (dispatch), cbf[m][np] bf16 (combine) ----------------
__global__ __launch_bounds__(256) void k_weights(const float* __restrict__ logitsT,
                                                 const float* __restrict__ cmax,
                                                 const float* __restrict__ cinv,
                                                 unsigned short* __restrict__ dvalT,
                                                 unsigned short* __restrict__ cbf) {
    const int b = blockIdx.y, m0 = blockIdx.x * 32;
    const int tid = threadIdx.x;
    __shared__ float lt[128][36];
    __shared__ float red[32][8];
    __shared__ float rstat[32][2];
    const int np = tid >> 1;
    const int mh = (tid & 1) * 16;
    const float cm = cmax[b * NP_ + np], ci = cinv[b * NP_ + np];
    unsigned short ev[16];
#pragma unroll
    for (int ii = 0; ii < 4; ++ii) {
        const int mq = mh + ii * 4;
        float4 v = *(const float4*)(logitsT + ((size_t)b * NP_ + np) * M_ + m0 + mq);
        *(float4*)&lt[np][mq] = v;
        ev[ii * 4 + 0] = f2bf(__expf(v.x - cm) * ci);
        ev[ii * 4 + 1] = f2bf(__expf(v.y - cm) * ci);
        ev[ii * 4 + 2] = f2bf(__expf(v.z - cm) * ci);
        ev[ii * 4 + 3] = f2bf(__expf(v.w - cm) * ci);
    }
    {
        unsigned short* dp = dvalT + ((size_t)b * NP_ + np) * M_ + m0 + mh;
        *(bf16x8*)dp = *(const bf16x8*)&ev[0];
        *(bf16x8*)(dp + 8) = *(const bf16x8*)&ev[8];
    }
    __syncthreads();
    const int mm = tid >> 3, g = tid & 7;
    float mx = -1e30f;
#pragma unroll
    for (int i = 0; i < 16; ++i) mx = fmaxf(mx, lt[g * 16 + i][mm]);
    red[mm][g] = mx;
    __syncthreads();
    if (g == 0) {
        float M2 = red[mm][0];
#pragma unroll
        for (int k = 1; k < 8; ++k) M2 = fmaxf(M2, red[mm][k]);
        rstat[mm][0] = M2;
    }
    __syncthreads();
    const float rm = rstat[mm][0];
    float s = 0.f;
#pragma unroll
    for (int i = 0; i < 16; ++i) s += __expf(lt[g * 16 + i][mm] - rm);
    red[mm][g] = s;
    __syncthreads();
    if (g == 0) {
        float S = 0.f;
#pragma unroll
        for (int k = 0; k < 8; ++k) S += red[mm][k];
        rstat[mm][1] = 1.0f / S;
    }
    __syncthreads();
    const float ri = rstat[mm][1];
    bf16x8 o0, o1;
#pragma unroll
    for (int i = 0; i < 8; ++i) o0[i] = (short)f2bf(__expf(lt[g * 16 + i][mm] - rm) * ri);
#pragma unroll
    for (int i = 0; i < 8; ++i) o1[i] = (short)f2bf(__expf(lt[g * 16 + 8 + i][mm] - rm) * ri);
    unsigned short* co = cbf + ((size_t)b * M_ + m0 + mm) * NP_ + g * 16;
    *(bf16x8*)(co) = o0;
    *(bf16x8*)(co + 8) = o1;
}

// ---------------- GEMM2: partial[kc][b][np][d] = dvalT-chunk . xbfT-chunk ----------------
// operand-swapped: A = xbfT (d rows), B = dvalT (np rows) -> C[d][np], float4 stores along d.
// tile 64d x 128np, split-K = 8 -> grid (16, 8, 8) = 1024 blocks (4 blocks/CU)
__global__ __launch_bounds__(256) void k_xs(const unsigned short* __restrict__ dvalT,
                                            const unsigned short* __restrict__ xbfT,
                                            float* __restrict__ partial) {
    const int dt = blockIdx.x, kc = blockIdx.y, b = blockIdx.z;
    const int d0 = dt * 64;
    const int tid = threadIdx.x, lane = tid & 63, w = tid >> 6;
    __shared__ char At[2][4096], Bt[2][8192];
    f32x4 acc[2][4] = {};
    const char* abase = (const char*)(xbfT + ((size_t)b * D_ + d0) * M_) + (size_t)kc * 1024;
    const char* bbase = (const char*)(dvalT + (size_t)b * NP_ * M_) + (size_t)kc * 1024;
    const int wmm = (w & 1) * 32, wnn = (w >> 1) * 64;
    const int fr = lane & 15, q = lane >> 4;
    stage_rows64(abase, (size_t)M_ * 2, At[0], tid);
    stage_tile(bbase, (size_t)M_ * 2, Bt[0], tid);
    __syncthreads();
    int cur = 0;
    for (int k0 = 64; k0 < 1024; k0 += 64) {
        stage_rows64(abase + k0, (size_t)M_ * 2, At[cur ^ 1], tid);
        stage_tile(bbase + k0, (size_t)M_ * 2, Bt[cur ^ 1], tid);
        mfma_tile<2, 4>(At[cur], Bt[cur], acc, wmm, wnn, fr, q);
        __syncthreads();
        cur ^= 1;
    }
    mfma_tile<2, 4>(At[cur], Bt[cur], acc, wmm, wnn, fr, q);
    // C[d][np]: d = d0 + wmm + i*16 + q*4 + reg, np = wnn + j*16 + fr
#pragma unroll
    for (int i = 0; i < 2; ++i) {
        const int dd = d0 + wmm + i * 16 + q * 4;
#pragma unroll
        for (int j = 0; j < 4; ++j) {
            const int np = wnn + j * 16 + fr;
            float4 o;
            o.x = acc[i][j][0]; o.y = acc[i][j][1]; o.z = acc[i][j][2]; o.w = acc[i][j][3];
            *(float4*)(partial + (((size_t)kc * B_ + b) * NP_ + np) * D_ + dd) = o;
        }
    }
}

// ---------------- reduce split-K partials (8) -> xs[b][np][d] fp32 ----------------
__global__ void k_xsred(const float* __restrict__ partial, float* __restrict__ xs) {
    const size_t i = ((size_t)blockIdx.x * 256 + threadIdx.x) * 4;
    const size_t CH = (size_t)B_ * NP_ * D_;
    float4 o = *(const float4*)(partial + i);
#pragma unroll
    for (int c = 1; c < 8; ++c) {
        float4 s = *(const float4*)(partial + (size_t)c * CH + i);
        o.x += s.x; o.y += s.y; o.z += s.z; o.w += s.w;
    }
    *(float4*)(xs + i) = o;
}

// ---------------- per-expert linear: ysT[b][e][np] bf16 = xs @ W[n] + bias[n] ----------------
__global__ __launch_bounds__(256) void k_ys(const float* __restrict__ xs,
                                            const float* __restrict__ W,
                                            const float* __restrict__ bias,
                                            unsigned short* __restrict__ ysT) {
    const int et = blockIdx.x;  // 8 tiles of 128 e
    const int n = blockIdx.y;   // 64
    const int e0 = et * 128;
    const int tid = threadIdx.x, tx = tid & 31, ty = tid >> 5;
    __shared__ float wt[32][128];
    __shared__ float xst[16][32];
    float acc[2][4];
#pragma unroll
    for (int j = 0; j < 2; ++j)
#pragma unroll
        for (int q = 0; q < 4; ++q) acc[j][q] = 0.f;
    const float* wbase = W + (size_t)n * D_ * D_;
    for (int k0 = 0; k0 < D_; k0 += 32) {
#pragma unroll
        for (int it = 0; it < 4; ++it) {
            int idx = tid + 256 * it;
            int row = idx >> 5, c4 = (idx & 31) * 4;
            *(float4*)(&wt[row][c4]) = *(const float4*)(wbase + (size_t)(k0 + row) * D_ + e0 + c4);
        }
        if (tid < 128) {
            int r = tid >> 3, c4 = (tid & 7) * 4;
            int bb = r >> 1, pp = r & 1;
            *(float4*)(&xst[r][c4]) =
                *(const float4*)(xs + ((size_t)bb * NP_ + n * 2 + pp) * D_ + k0 + c4);
        }
        __syncthreads();
#pragma unroll
        for (int k = 0; k < 32; ++k) {
            float4 w4 = *(const float4*)(&wt[k][tx * 4]);
            float r0 = xst[ty * 2][k], r1 = xst[ty * 2 + 1][k];
            acc[0][0] += r0 * w4.x; acc[0][1] += r0 * w4.y;
            acc[0][2] += r0 * w4.z; acc[0][3] += r0 * w4.w;
            acc[1][0] += r1 * w4.x; acc[1][1] += r1 * w4.y;
            acc[1][2] += r1 * w4.z; acc[1][3] += r1 * w4.w;
        }
        __syncthreads();
    }
    float4 bv = *(const float4*)(bias + n * D_ + e0 + tx * 4);
#pragma unroll
    for (int j = 0; j < 2; ++j) {
        const int r = ty * 2 + j;
        const int bb = r >> 1, pp = r & 1;
        float v0 = acc[j][0] + bv.x, v1 = acc[j][1] + bv.y;
        float v2 = acc[j][2] + bv.z, v3 = acc[j][3] + bv.w;
        ysT[((size_t)bb * D_ + e0 + tx * 4 + 0) * NP_ + n * 2 + pp] = f2bf(v0);
        ysT[((size_t)bb * D_ + e0 + tx * 4 + 1) * NP_ + n * 2 + pp] = f2bf(v1);
        ysT[((size_t)bb * D_ + e0 + tx * 4 + 2) * NP_ + n * 2 + pp] = f2bf(v2);
        ysT[((size_t)bb * D_ + e0 + tx * 4 + 3) * NP_ + n * 2 + pp] = f2bf(v3);
    }
}

// ---------------- GEMM3: out[b][m][e] = cbf . ysT + x ----------------
// operand-swapped: A = ysT (e rows), B = cbf (m rows) -> C[e][m], float4 out/x along e.
__global__ __launch_bounds__(256) void k_final(const unsigned short* __restrict__ cbf,
                                               const unsigned short* __restrict__ ysT,
                                               const float* __restrict__ x,
                                               float* __restrict__ out) {
    const int et = blockIdx.x, mt = blockIdx.y, b = blockIdx.z;
    const int e0 = et * 128, m0 = mt * 128;
    const int tid = threadIdx.x, lane = tid & 63, w = tid >> 6;
    __shared__ char At[2][8192], Bt[2][8192];
    f32x4 acc[4][4] = {};
    const char* abase = (const char*)(ysT + ((size_t)b * D_ + e0) * NP_);  // e rows, stride 256 B
    const char* bbase = (const char*)(cbf + ((size_t)b * M_ + m0) * NP_);  // m rows, stride 256 B
    const int wmm = (w & 1) * 64, wnn = (w >> 1) * 64;
    const int fr = lane & 15, q = lane >> 4;
    stage_tile(abase, 256, At[0], tid);
    stage_tile(bbase, 256, Bt[0], tid);
    __syncthreads();
    int cur = 0;
    for (int k0 = 64; k0 < 256; k0 += 64) {
        stage_tile(abase + k0, 256, At[cur ^ 1], tid);
        stage_tile(bbase + k0, 256, Bt[cur ^ 1], tid);
        mfma_tile<4, 4>(At[cur], Bt[cur], acc, wmm, wnn, fr, q);
        __syncthreads();
        cur ^= 1;
    }
    mfma_tile<4, 4>(At[cur], Bt[cur], acc, wmm, wnn, fr, q);
    // C[e][m]: e = e0 + wmm + i*16 + q*4 + reg, m = m0 + wnn + j*16 + fr
#pragma unroll
    for (int i = 0; i < 4; ++i) {
        const int e = e0 + wmm + i * 16 + q * 4;
#pragma unroll
        for (int j = 0; j < 4; ++j) {
            const int m = m0 + wnn + j * 16 + fr;
            const size_t idx = ((size_t)b * M_ + m) * D_ + e;
            float4 xv = *(const float4*)(x + idx);
            float4 o;
            o.x = acc[i][j][0] + xv.x;
            o.y = acc[i][j][1] + xv.y;
            o.z = acc[i][j][2] + xv.z;
            o.w = acc[i][j][3] + xv.w;
            *(float4*)(out + idx) = o;
        }
    }
}

extern "C" void kernel_launch(void* const* d_in, const int* in_sizes, int n_in,
                              void* d_out, int out_size, void* d_ws, size_t ws_size,
                              hipStream_t stream) {
    const float* x = (const float*)d_in[0];
    const float* phi = (const float*)d_in[1];
    const float* scale = (const float*)d_in[2];
    const float* W = (const float*)d_in[3];
    const float* bias = (const float*)d_in[4];
    float* out = (float*)d_out;

    char* ws = (char*)d_ws;
    float* rinv = (float*)ws;                                   // 131072 B
    float* cmax = (float*)(ws + 131072);                        // 4096 B
    float* cinv = (float*)(ws + 135168);                        // 4096 B
    unsigned short* phinT = (unsigned short*)(ws + 139264);     // 262144 B
    unsigned short* xbf = (unsigned short*)(ws + 401408);       // 64 MiB
    unsigned short* xbfT = (unsigned short*)(ws + 401408 + 67108864);   // 64 MiB
    float* logitsT = (float*)(ws + 401408 + 134217728);         // 16 MiB
    unsigned short* dvalT = (unsigned short*)(ws + 401408 + 150994944);  // 8 MiB
    unsigned short* cbf = (unsigned short*)(ws + 401408 + 159383552);    // 8 MiB
    // aliases (lifetime-disjoint) — all inside the dead xbf region (64 MiB):
    float* partial = (float*)xbf;                                   // 32 MiB (8 chunks)
    float* xs = (float*)((char*)xbf + 33554432);                    // 4 MiB
    unsigned short* ysT = (unsigned short*)((char*)xbf + 37748736); // 2 MiB

    k_prepT<<<512, 256, 0, stream>>>(x, xbf, xbfT, rinv);
    k_phin<<<128, 256, 0, stream>>>(phi, scale, phinT);
    k_logits<<<dim3(64, 2, 8), 256, 0, stream>>>(phinT, xbf, rinv, logitsT);
    k_colstats<<<256, 256, 0, stream>>>(logitsT, cmax, cinv);
    k_weights<<<dim3(128, 8), 256, 0, stream>>>(logitsT, cmax, cinv, dvalT, cbf);
    k_xs<<<dim3(16, 8, 8), 256, 0, stream>>>(dvalT, xbfT, partial);
    k_xsred<<<1024, 256, 0, stream>>>(partial, xs);
    k_ys<<<dim3(8, 64), 256, 0, stream>>>(xs, W, bias, ysT);
    k_final<<<dim3(8, 32, 8), 256, 0, stream>>>(cbf, ysT, x, out);
}

// Round 3
// 681.402 us; speedup vs baseline: 1.0185x; 1.0185x over previous
//
#include <hip/hip_runtime.h>
#include <hip/hip_bf16.h>
#include <math.h>

#define B_ 8
#define M_ 4096
#define D_ 1024
#define NP_ 128
#define TEMP_ 0.1f
#define EPS_ 1e-12f

typedef __attribute__((ext_vector_type(8))) short bf16x8;
typedef __attribute__((ext_vector_type(4))) float f32x4;

__device__ __forceinline__ unsigned short f2bf(float f) {
    union { float f; unsigned int u; } v; v.f = f;
    unsigned int u = v.u;
    u += 0x7fff + ((u >> 16) & 1);  // RNE
    return (unsigned short)(u >> 16);
}

// ---- swizzled staging: rows of 128 B. LDS dest linear; global source col pre-swizzled
// (rule #21: linear dest + inverse-swizzled source + swizzled read = consistent involution).
template <int R>
__device__ __forceinline__ void stage128s(const char* gbase, size_t row_stride,
                                          char* lds, int tid) {
#pragma unroll
    for (int it = 0; it < R / 32; ++it) {
        const int g = tid + 256 * it;
        const int row = g >> 3;
        const int scol = ((g & 7) * 16) ^ ((row & 7) << 4);
        const char* gp = gbase + (size_t)row * row_stride + scol;
        __builtin_amdgcn_global_load_lds((const __attribute__((address_space(1))) unsigned int*)gp,
                                         (__attribute__((address_space(3))) unsigned int*)(lds + g * 16),
                                         16, 0, 0);
    }
}

// rows of 256 B variant
template <int R>
__device__ __forceinline__ void stage256s(const char* gbase, size_t row_stride,
                                          char* lds, int tid) {
#pragma unroll
    for (int it = 0; it < R / 16; ++it) {
        const int g = tid + 256 * it;
        const int row = g >> 4;
        const int scol = ((g & 15) * 16) ^ ((row & 7) << 4);
        const char* gp = gbase + (size_t)row * row_stride + scol;
        __builtin_amdgcn_global_load_lds((const __attribute__((address_space(1))) unsigned int*)gp,
                                         (__attribute__((address_space(3))) unsigned int*)(lds + g * 16),
                                         16, 0, 0);
    }
}

// MFMA over a BK=128B (64-elem) K-step; swizzled fragment reads
template <int NI, int NJ>
__device__ __forceinline__ void mfma128(const char* At, const char* Bt,
                                        f32x4 (&acc)[NI][NJ], int wm, int wn,
                                        int fr, int q) {
#pragma unroll
    for (int ks = 0; ks < 2; ++ks) {
        bf16x8 a[NI], bb[NJ];
#pragma unroll
        for (int i = 0; i < NI; ++i) {
            const int row = wm + i * 16 + fr;
            a[i] = *(const bf16x8*)(At + ((row * 128 + ks * 64 + q * 16) ^ ((row & 7) << 4)));
        }
#pragma unroll
        for (int j = 0; j < NJ; ++j) {
            const int row = wn + j * 16 + fr;
            bb[j] = *(const bf16x8*)(Bt + ((row * 128 + ks * 64 + q * 16) ^ ((row & 7) << 4)));
        }
#pragma unroll
        for (int i = 0; i < NI; ++i)
#pragma unroll
            for (int j = 0; j < NJ; ++j)
                acc[i][j] = __builtin_amdgcn_mfma_f32_16x16x32_bf16(a[i], bb[j], acc[i][j], 0, 0, 0);
    }
}

// MFMA over a 256B-row tile (K=128 elem total, 4 slices)
template <int NI, int NJ>
__device__ __forceinline__ void mfma256(const char* At, const char* Bt,
                                        f32x4 (&acc)[NI][NJ], int wm, int wn,
                                        int fr, int q) {
#pragma unroll
    for (int ks = 0; ks < 4; ++ks) {
        bf16x8 a[NI], bb[NJ];
#pragma unroll
        for (int i = 0; i < NI; ++i) {
            const int row = wm + i * 16 + fr;
            a[i] = *(const bf16x8*)(At + ((row * 256 + ks * 64 + q * 16) ^ ((row & 7) << 4)));
        }
#pragma unroll
        for (int j = 0; j < NJ; ++j) {
            const int row = wn + j * 16 + fr;
            bb[j] = *(const bf16x8*)(Bt + ((row * 256 + ks * 64 + q * 16) ^ ((row & 7) << 4)));
        }
#pragma unroll
        for (int i = 0; i < NI; ++i)
#pragma unroll
            for (int j = 0; j < NJ; ++j)
                acc[i][j] = __builtin_amdgcn_mfma_f32_16x16x32_bf16(a[i], bb[j], acc[i][j], 0, 0, 0);
    }
}

// ---------------- prep: rinv + bf16 cast (xbf[m][d]) + bf16 transpose (xbfT[d][m]) ----------------
// LDS transpose with XOR swizzle: fixes 8-way bank conflict on the scattered ushort stores.
__global__ __launch_bounds__(256) void k_prepT(const float* __restrict__ x,
                                               unsigned short* __restrict__ xbf,
                                               unsigned short* __restrict__ xbfT,
                                               float* __restrict__ rinv) {
    const int p = blockIdx.x;
    const int b = p >> 6, m0 = (p & 63) * 64;
    const int tid = threadIdx.x;
    const int mg = tid >> 4;   // 0..15
    const int d4 = tid & 15;   // 0..15
    __shared__ char ltb[2][64 * 144];
    float ss[4] = {0.f, 0.f, 0.f, 0.f};
    const int skey = (d4 & 7) << 4;  // swizzle key for store rows d4*4..d4*4+3 (row>>2 == d4)
    for (int ch = 0; ch < 16; ++ch) {
        const int d0 = ch * 64;
        const int buf = ch & 1;
#pragma unroll
        for (int ii = 0; ii < 4; ++ii) {
            const int m = mg + ii * 16;
            float4 v = *(const float4*)(x + ((size_t)(b * M_ + m0 + m)) * D_ + d0 + d4 * 4);
            ss[ii] += v.x * v.x + v.y * v.y + v.z * v.z + v.w * v.w;
            ushort4 bv;
            bv.x = f2bf(v.x); bv.y = f2bf(v.y); bv.z = f2bf(v.z); bv.w = f2bf(v.w);
            *(ushort4*)(xbf + ((size_t)(b * M_ + m0 + m)) * D_ + d0 + d4 * 4) = bv;
            const int r0 = d4 * 4;
            *(unsigned short*)(ltb[buf] + (((r0 + 0) * 144 + m * 2) ^ skey)) = bv.x;
            *(unsigned short*)(ltb[buf] + (((r0 + 1) * 144 + m * 2) ^ skey)) = bv.y;
            *(unsigned short*)(ltb[buf] + (((r0 + 2) * 144 + m * 2) ^ skey)) = bv.z;
            *(unsigned short*)(ltb[buf] + (((r0 + 3) * 144 + m * 2) ^ skey)) = bv.w;
        }
        __syncthreads();
        const int dl = tid >> 2, mq = (tid & 3) * 16;
        const int rkey = ((dl >> 2) & 7) << 4;
        bf16x8 v0 = *(const bf16x8*)(ltb[buf] + ((dl * 144 + mq * 2) ^ rkey));
        bf16x8 v1 = *(const bf16x8*)(ltb[buf] + ((dl * 144 + mq * 2 + 16) ^ rkey));
        unsigned short* to = xbfT + ((size_t)(b * D_ + d0 + dl)) * M_ + m0 + mq;
        *(bf16x8*)(to) = v0;
        *(bf16x8*)(to + 8) = v1;
        // no second barrier: next chunk writes the other buffer
    }
#pragma unroll
    for (int ii = 0; ii < 4; ++ii) {
        float s = ss[ii];
        s += __shfl_down(s, 8, 16);
        s += __shfl_down(s, 4, 16);
        s += __shfl_down(s, 2, 16);
        s += __shfl_down(s, 1, 16);
        if (d4 == 0)
            rinv[b * M_ + m0 + mg + ii * 16] = 1.0f / (fmaxf(sqrtf(s), EPS_) * TEMP_);
    }
}

// ---------------- phi normalize -> phinT[np][d] bf16 ----------------
__global__ void k_phin(const float* __restrict__ phi, const float* __restrict__ scale,
                       unsigned short* __restrict__ phinT) {
    const int np = blockIdx.x, tid = threadIdx.x;
    float ss = 0.f;
    for (int d = tid; d < D_; d += 256) {
        float v = phi[d * NP_ + np];
        ss += v * v;
    }
    __shared__ float red[256];
    red[tid] = ss;
    __syncthreads();
    for (int s = 128; s > 0; s >>= 1) {
        if (tid < s) red[tid] += red[tid + s];
        __syncthreads();
    }
    float inv = scale[0] / fmaxf(sqrtf(red[0]), EPS_);
    for (int d = tid; d < D_; d += 256) phinT[np * D_ + d] = f2bf(phi[d * NP_ + np] * inv);
}

// ---------------- GEMM1: logitsT[b][np][m] = (xbf . phinT) * rinv[m] ----------------
// A = xbf (64 m rows), B = phinT (128 np rows): C[m][np], float4 stores along m.
// BK=128B, grid (64, 8) = 512 blocks (2/CU), LDS 48 KB.
__global__ __launch_bounds__(256) void k_logits(const unsigned short* __restrict__ phinT,
                                                const unsigned short* __restrict__ xbf,
                                                const float* __restrict__ rinv,
                                                float* __restrict__ logitsT) {
    const int m0 = blockIdx.x * 64;
    const int b = blockIdx.y;
    const int tid = threadIdx.x, lane = tid & 63, w = tid >> 6;
    __shared__ char At[2][8192], Bt[2][16384];
    f32x4 acc[2][4] = {};
    const char* abase = (const char*)(xbf + ((size_t)b * M_ + m0) * D_);  // 64 m rows, stride 2048
    const char* bbase = (const char*)phinT;                               // 128 np rows, stride 2048
    const int wm = (w & 1) * 32, wn = (w >> 1) * 64;
    const int fr = lane & 15, q = lane >> 4;
    stage128s<64>(abase, 2048, At[0], tid);
    stage128s<128>(bbase, 2048, Bt[0], tid);
    __syncthreads();
    int cur = 0;
    for (int k0 = 128; k0 < 2048; k0 += 128) {
        stage128s<64>(abase + k0, 2048, At[cur ^ 1], tid);
        stage128s<128>(bbase + k0, 2048, Bt[cur ^ 1], tid);
        mfma128<2, 4>(At[cur], Bt[cur], acc, wm, wn, fr, q);
        __syncthreads();
        cur ^= 1;
    }
    mfma128<2, 4>(At[cur], Bt[cur], acc, wm, wn, fr, q);
    // C[m][np]: m = m0 + wm + i*16 + q*4 + reg, np = wn + j*16 + fr
#pragma unroll
    for (int i = 0; i < 2; ++i) {
        const int mm = wm + i * 16 + q * 4;
        const float4 rv = *(const float4*)(rinv + (size_t)b * M_ + m0 + mm);
#pragma unroll
        for (int j = 0; j < 4; ++j) {
            const int np = wn + j * 16 + fr;
            float4 o;
            o.x = acc[i][j][0] * rv.x;
            o.y = acc[i][j][1] * rv.y;
            o.z = acc[i][j][2] * rv.z;
            o.w = acc[i][j][3] * rv.w;
            *(float4*)(logitsT + ((size_t)b * NP_ + np) * M_ + m0 + mm) = o;
        }
    }
}

// ---------------- dispatch softmax stats over m (rows of logitsT) ----------------
__global__ void k_colstats(const float* __restrict__ logitsT, float* __restrict__ cmax,
                           float* __restrict__ cinv) {
    const int row = blockIdx.x * 4 + (threadIdx.x >> 6);  // b*128+np
    const int lane = threadIdx.x & 63;
    const float4* base = (const float4*)(logitsT + (size_t)row * M_);
    float mx = -1e30f, sm = 0.f;
#pragma unroll 4
    for (int it = 0; it < 16; ++it) {
        float4 v = base[lane + 64 * it];
        float lm = fmaxf(fmaxf(v.x, v.y), fmaxf(v.z, v.w));
        float nm = fmaxf(mx, lm);
        sm = sm * __expf(mx - nm) + __expf(v.x - nm) + __expf(v.y - nm) + __expf(v.z - nm) +
             __expf(v.w - nm);
        mx = nm;
    }
    for (int off = 32; off > 0; off >>= 1) {
        float om = __shfl_down(mx, off), os = __shfl_down(sm, off);
        float nm = fmaxf(mx, om);
        sm = sm * __expf(mx - nm) + os * __expf(om - nm);
        mx = nm;
    }
    if (lane == 0) {
        cmax[row] = mx;
        cinv[row] = 1.0f / sm;
    }
}

// ---------------- weights: dvalT[np][m] bf16 (dispatch), cbf[m][np] bf16 (combine) ----------------
__global__ __launch_bounds__(256) void k_weights(const float* __restrict__ logitsT,
                                                 const float* __restrict__ cmax,
                                                 const float* __restrict__ cinv,
                                                 unsigned short* __restrict__ dvalT,
                                                 unsigned short* __restrict__ cbf) {
    const int b = blockIdx.y, m0 = blockIdx.x * 32;
    const int tid = threadIdx.x;
    __shared__ float lt[128][36];
    __shared__ float red[32][8];
    __shared__ float rstat[32][2];
    const int np = tid >> 1;
    const int mh = (tid & 1) * 16;
    const float cm = cmax[b * NP_ + np], ci = cinv[b * NP_ + np];
    unsigned short ev[16];
#pragma unroll
    for (int ii = 0; ii < 4; ++ii) {
        const int mq = mh + ii * 4;
        float4 v = *(const float4*)(logitsT + ((size_t)b * NP_ + np) * M_ + m0 + mq);
        *(float4*)&lt[np][mq] = v;
        ev[ii * 4 + 0] = f2bf(__expf(v.x - cm) * ci);
        ev[ii * 4 + 1] = f2bf(__expf(v.y - cm) * ci);
        ev[ii * 4 + 2] = f2bf(__expf(v.z - cm) * ci);
        ev[ii * 4 + 3] = f2bf(__expf(v.w - cm) * ci);
    }
    {
        unsigned short* dp = dvalT + ((size_t)b * NP_ + np) * M_ + m0 + mh;
        *(bf16x8*)dp = *(const bf16x8*)&ev[0];
        *(bf16x8*)(dp + 8) = *(const bf16x8*)&ev[8];
    }
    __syncthreads();
    const int mm = tid >> 3, g = tid & 7;
    float mx = -1e30f;
#pragma unroll
    for (int i = 0; i < 16; ++i) mx = fmaxf(mx, lt[g * 16 + i][mm]);
    red[mm][g] = mx;
    __syncthreads();
    if (g == 0) {
        float M2 = red[mm][0];
#pragma unroll
        for (int k = 1; k < 8; ++k) M2 = fmaxf(M2, red[mm][k]);
        rstat[mm][0] = M2;
    }
    __syncthreads();
    const float rm = rstat[mm][0];
    float s = 0.f;
#pragma unroll
    for (int i = 0; i < 16; ++i) s += __expf(lt[g * 16 + i][mm] - rm);
    red[mm][g] = s;
    __syncthreads();
    if (g == 0) {
        float S = 0.f;
#pragma unroll
        for (int k = 0; k < 8; ++k) S += red[mm][k];
        rstat[mm][1] = 1.0f / S;
    }
    __syncthreads();
    const float ri = rstat[mm][1];
    bf16x8 o0, o1;
#pragma unroll
    for (int i = 0; i < 8; ++i) o0[i] = (short)f2bf(__expf(lt[g * 16 + i][mm] - rm) * ri);
#pragma unroll
    for (int i = 0; i < 8; ++i) o1[i] = (short)f2bf(__expf(lt[g * 16 + 8 + i][mm] - rm) * ri);
    unsigned short* co = cbf + ((size_t)b * M_ + m0 + mm) * NP_ + g * 16;
    *(bf16x8*)(co) = o0;
    *(bf16x8*)(co + 8) = o1;
}

// ---------------- GEMM2: partial[kc][b][np][d] = xbfT-chunk . dvalT-chunk ----------------
// A = xbfT (64 d rows), B = dvalT (128 np rows): C[d][np], float4 stores along d.
// split-K = 4, grid (16, 4, 8) = 512 blocks, BK=128B, 16 iters, LDS 48 KB.
__global__ __launch_bounds__(256) void k_xs(const unsigned short* __restrict__ dvalT,
                                            const unsigned short* __restrict__ xbfT,
                                            float* __restrict__ partial) {
    const int dt = blockIdx.x, kc = blockIdx.y, b = blockIdx.z;
    const int d0 = dt * 64;
    const int tid = threadIdx.x, lane = tid & 63, w = tid >> 6;
    __shared__ char At[2][8192], Bt[2][16384];
    f32x4 acc[2][4] = {};
    const char* abase = (const char*)(xbfT + ((size_t)b * D_ + d0) * M_) + (size_t)kc * 2048;
    const char* bbase = (const char*)(dvalT + (size_t)b * NP_ * M_) + (size_t)kc * 2048;
    const int wm = (w & 1) * 32, wn = (w >> 1) * 64;
    const int fr = lane & 15, q = lane >> 4;
    stage128s<64>(abase, (size_t)M_ * 2, At[0], tid);
    stage128s<128>(bbase, (size_t)M_ * 2, Bt[0], tid);
    __syncthreads();
    int cur = 0;
    for (int k0 = 128; k0 < 2048; k0 += 128) {
        stage128s<64>(abase + k0, (size_t)M_ * 2, At[cur ^ 1], tid);
        stage128s<128>(bbase + k0, (size_t)M_ * 2, Bt[cur ^ 1], tid);
        mfma128<2, 4>(At[cur], Bt[cur], acc, wm, wn, fr, q);
        __syncthreads();
        cur ^= 1;
    }
    mfma128<2, 4>(At[cur], Bt[cur], acc, wm, wn, fr, q);
    // C[d][np]: d = d0 + wm + i*16 + q*4 + reg, np = wn + j*16 + fr
#pragma unroll
    for (int i = 0; i < 2; ++i) {
        const int dd = d0 + wm + i * 16 + q * 4;
#pragma unroll
        for (int j = 0; j < 4; ++j) {
            const int np = wn + j * 16 + fr;
            float4 o;
            o.x = acc[i][j][0]; o.y = acc[i][j][1]; o.z = acc[i][j][2]; o.w = acc[i][j][3];
            *(float4*)(partial + (((size_t)kc * B_ + b) * NP_ + np) * D_ + dd) = o;
        }
    }
}

// ---------------- reduce split-K partials (4) -> xsT[n][k][slot16] fp32 ----------------
__global__ void k_xsred(const float* __restrict__ partial, float* __restrict__ xsT) {
    const size_t i = ((size_t)blockIdx.x * 256 + threadIdx.x) * 4;
    const size_t CH = (size_t)B_ * NP_ * D_;
    float4 o = *(const float4*)(partial + i);
#pragma unroll
    for (int c = 1; c < 4; ++c) {
        float4 s = *(const float4*)(partial + (size_t)c * CH + i);
        o.x += s.x; o.y += s.y; o.z += s.z; o.w += s.w;
    }
    const int d = (int)(i % D_);
    const int np = (int)((i / D_) % NP_);
    const int b = (int)(i / ((size_t)D_ * NP_));
    const int n = np >> 1, pp = np & 1, slot = b * 2 + pp;
    float* xp = xsT + ((size_t)n * D_ + d) * 16 + slot;
    xp[0] = o.x;
    xp[16] = o.y;
    xp[32] = o.z;
    xp[48] = o.w;
}

// ---------------- per-expert linear: ysT[b][e][np] bf16 = xs @ W[n] + bias[n] ----------------
// LDS-free: W streamed to VGPRs (lane owns 2 e), xsT slots via uniform s_load.
// grid (8 e-tiles, 64 n) = 512 blocks; wave w handles slots w*4..w*4+3.
__global__ __launch_bounds__(256) void k_ys(const float* __restrict__ xsT,
                                            const float* __restrict__ W,
                                            const float* __restrict__ bias,
                                            unsigned short* __restrict__ ysT) {
    const int et = blockIdx.x;
    const int n = blockIdx.y;
    const int tid = threadIdx.x, lane = tid & 63;
    const int wu = __builtin_amdgcn_readfirstlane(tid >> 6);  // slot group 0..3 (uniform)
    const int e = et * 128 + lane * 2;
    const float* wb = W + (size_t)n * D_ * D_ + e;
    const float* sb = xsT + (size_t)n * D_ * 16 + wu * 4;
    float acc[4][2] = {};
#pragma unroll 8
    for (int k = 0; k < D_; ++k) {
        float2 wv = *(const float2*)(wb + (size_t)k * D_);
        float4 sv = *(const float4*)(sb + (size_t)k * 16);
        acc[0][0] = fmaf(sv.x, wv.x, acc[0][0]); acc[0][1] = fmaf(sv.x, wv.y, acc[0][1]);
        acc[1][0] = fmaf(sv.y, wv.x, acc[1][0]); acc[1][1] = fmaf(sv.y, wv.y, acc[1][1]);
        acc[2][0] = fmaf(sv.z, wv.x, acc[2][0]); acc[2][1] = fmaf(sv.z, wv.y, acc[2][1]);
        acc[3][0] = fmaf(sv.w, wv.x, acc[3][0]); acc[3][1] = fmaf(sv.w, wv.y, acc[3][1]);
    }
    float2 bv = *(const float2*)(bias + n * D_ + e);
#pragma unroll
    for (int s = 0; s < 4; ++s) {
        const int slot = wu * 4 + s;
        const int b = slot >> 1, pp = slot & 1;
        ysT[((size_t)b * D_ + e) * NP_ + n * 2 + pp] = f2bf(acc[s][0] + bv.x);
        ysT[((size_t)b * D_ + e + 1) * NP_ + n * 2 + pp] = f2bf(acc[s][1] + bv.y);
    }
}

// ---------------- GEMM3: out[b][m][e] = ysT . cbf + x ----------------
// A = ysT (128 e rows), B = cbf (128 m rows): C[e][m], float4 x/out along e.
// single-stage (K=128 elem = 256 B rows), ONE barrier, LDS 64 KB.
__global__ __launch_bounds__(256) void k_final(const unsigned short* __restrict__ cbf,
                                               const unsigned short* __restrict__ ysT,
                                               const float* __restrict__ x,
                                               float* __restrict__ out) {
    const int et = blockIdx.x, mt = blockIdx.y, b = blockIdx.z;
    const int e0 = et * 128, m0 = mt * 128;
    const int tid = threadIdx.x, lane = tid & 63, w = tid >> 6;
    __shared__ char At[32768], Bt[32768];
    f32x4 acc[4][4] = {};
    const char* abase = (const char*)(ysT + ((size_t)b * D_ + e0) * NP_);  // e rows, 256 B
    const char* bbase = (const char*)(cbf + ((size_t)b * M_ + m0) * NP_);  // m rows, 256 B
    const int wm = (w & 1) * 64, wn = (w >> 1) * 64;
    const int fr = lane & 15, q = lane >> 4;
    stage256s<128>(abase, 256, At, tid);
    stage256s<128>(bbase, 256, Bt, tid);
    __syncthreads();
    mfma256<4, 4>(At, Bt, acc, wm, wn, fr, q);
    // C[e][m]: e = e0 + wm + i*16 + q*4 + reg, m = m0 + wn + j*16 + fr
#pragma unroll
    for (int i = 0; i < 4; ++i) {
        const int e = e0 + wm + i * 16 + q * 4;
#pragma unroll
        for (int j = 0; j < 4; ++j) {
            const int m = m0 + wn + j * 16 + fr;
            const size_t idx = ((size_t)b * M_ + m) * D_ + e;
            float4 xv = *(const float4*)(x + idx);
            float4 o;
            o.x = acc[i][j][0] + xv.x;
            o.y = acc[i][j][1] + xv.y;
            o.z = acc[i][j][2] + xv.z;
            o.w = acc[i][j][3] + xv.w;
            *(float4*)(out + idx) = o;
        }
    }
}

extern "C" void kernel_launch(void* const* d_in, const int* in_sizes, int n_in,
                              void* d_out, int out_size, void* d_ws, size_t ws_size,
                              hipStream_t stream) {
    const float* x = (const float*)d_in[0];
    const float* phi = (const float*)d_in[1];
    const float* scale = (const float*)d_in[2];
    const float* W = (const float*)d_in[3];
    const float* bias = (const float*)d_in[4];
    float* out = (float*)d_out;

    char* ws = (char*)d_ws;
    float* rinv = (float*)ws;                                   // 131072 B
    float* cmax = (float*)(ws + 131072);                        // 4096 B
    float* cinv = (float*)(ws + 135168);                        // 4096 B
    unsigned short* phinT = (unsigned short*)(ws + 139264);     // 262144 B
    unsigned short* xbf = (unsigned short*)(ws + 401408);       // 64 MiB
    unsigned short* xbfT = (unsigned short*)(ws + 401408 + 67108864);   // 64 MiB
    float* logitsT = (float*)(ws + 401408 + 134217728);         // 16 MiB
    unsigned short* dvalT = (unsigned short*)(ws + 401408 + 150994944);  // 8 MiB
    unsigned short* cbf = (unsigned short*)(ws + 401408 + 159383552);    // 8 MiB
    // aliases (lifetime-disjoint) — inside the dead xbf region (64 MiB):
    float* partial = (float*)xbf;                                    // 16 MiB (4 chunks)
    float* xsT = (float*)((char*)xbf + 16777216);                    // 4 MiB  [n][k][slot16]
    unsigned short* ysT = (unsigned short*)((char*)xbf + 20971520);  // 2 MiB

    k_prepT<<<512, 256, 0, stream>>>(x, xbf, xbfT, rinv);
    k_phin<<<128, 256, 0, stream>>>(phi, scale, phinT);
    k_logits<<<dim3(64, 8), 256, 0, stream>>>(phinT, xbf, rinv, logitsT);
    k_colstats<<<256, 256, 0, stream>>>(logitsT, cmax, cinv);
    k_weights<<<dim3(128, 8), 256, 0, stream>>>(logitsT, cmax, cinv, dvalT, cbf);
    k_xs<<<dim3(16, 4, 8), 256, 0, stream>>>(dvalT, xbfT, partial);
    k_xsred<<<1024, 256, 0, stream>>>(partial, xsT);
    k_ys<<<dim3(8, 64), 256, 0, stream>>>(xsT, W, bias, ysT);
    k_final<<<dim3(8, 32, 8), 256, 0, stream>>>(cbf, ysT, x, out);
}